// Round 12
// baseline (313.873 us; speedup 1.0000x reference)
//
#include <hip/hip_runtime.h>
#include <hip/hip_bf16.h>
#include <cstdint>
#include <cstddef>

#define NNODES 100000
#define NEDGES 1600000
#define IN_DIM 256
#define HID 128
#define HEADS 8
#define DH 16
#define NCLS 64
#define SLOPE 0.2f

#define NBUCK 391              // (NNODES+255)>>8, 256 nodes per bucket
#define EPB 2000               // edges per block in bucket passes (800*2000 = E)
#define NBBLK 800

typedef __attribute__((ext_vector_type(8))) short bf16x8;
typedef __attribute__((ext_vector_type(4))) float f32x4;

static __device__ __forceinline__ unsigned short f2bf(float f) {
    __hip_bfloat16 h = __float2bfloat16(f);
    unsigned short r;
    __builtin_memcpy(&r, &h, sizeof(r));
    return r;
}
static __device__ __forceinline__ float bflo(unsigned int w) {
    union { uint32_t u; float f; } c; c.u = w << 16; return c.f;
}
static __device__ __forceinline__ float bfhi(unsigned int w) {
    union { uint32_t u; float f; } c; c.u = w & 0xFFFF0000u; return c.f;
}

// ---------------- W1 -> W1T bf16 [HID][IN_DIM] ----------------
__global__ __launch_bounds__(256) void prep_w1t_kernel(const float* __restrict__ W1,
                                                       short* __restrict__ W1T) {
    int idx = blockIdx.x * 256 + threadIdx.x;
    if (idx >= IN_DIM * HID) return;
    int k = idx >> 7;
    int n = idx & 127;
    W1T[n * IN_DIM + k] = (short)f2bf(W1[idx]);
}

// ---------------- W2 -> W2T bf16 [NCLS][HID] ----------------
__global__ __launch_bounds__(256) void prep_w2t_kernel(const float* __restrict__ W2,
                                                       short* __restrict__ W2T) {
    int idx = blockIdx.x * 256 + threadIdx.x;
    if (idx >= HID * NCLS) return;
    int k = idx >> 6;
    int n = idx & 63;
    W2T[n * HID + k] = (short)f2bf(W2[idx]);
}

// ---------------- bf16 MFMA GEMM1: h1b = x @ W1 (bf16 out), fused el1/er1 ----------------
__global__ __launch_bounds__(256) void gemm1_kernel(const float* __restrict__ x,
                                                    const short* __restrict__ W1T,
                                                    const float* __restrict__ al1,
                                                    const float* __restrict__ ar1,
                                                    unsigned short* __restrict__ h1b,
                                                    float* __restrict__ el1,
                                                    float* __restrict__ er1) {
    __shared__ short Asl[128 * 40];
    const int tid = threadIdx.x;
    const int brow = blockIdx.x * 128;
    const int wid = tid >> 6, lane = tid & 63;
    const int wm = (wid >> 1) * 64, wn = (wid & 1) * 64;
    const int mr = lane & 15;
    const int ks = lane >> 4;
    const int sr = tid >> 1;
    const int sch = tid & 1;
    const int grow = brow + sr;
    const bool rowok = grow < NNODES;
    const float* xrow = x + (size_t)grow * IN_DIM + sch * 16;

    f32x4 acc[4][4];
#pragma unroll
    for (int i = 0; i < 4; ++i)
#pragma unroll
        for (int j = 0; j < 4; ++j) acc[i][j] = (f32x4){0.f, 0.f, 0.f, 0.f};

    float4 v0 = {0,0,0,0}, v1 = {0,0,0,0}, v2 = {0,0,0,0}, v3 = {0,0,0,0};
    if (rowok) {
        v0 = *(const float4*)(xrow + 0);
        v1 = *(const float4*)(xrow + 4);
        v2 = *(const float4*)(xrow + 8);
        v3 = *(const float4*)(xrow + 12);
    }

    for (int k0 = 0; k0 < IN_DIM; k0 += 32) {
        bf16x8 p0, p1;
        p0[0] = (short)f2bf(v0.x); p0[1] = (short)f2bf(v0.y);
        p0[2] = (short)f2bf(v0.z); p0[3] = (short)f2bf(v0.w);
        p0[4] = (short)f2bf(v1.x); p0[5] = (short)f2bf(v1.y);
        p0[6] = (short)f2bf(v1.z); p0[7] = (short)f2bf(v1.w);
        p1[0] = (short)f2bf(v2.x); p1[1] = (short)f2bf(v2.y);
        p1[2] = (short)f2bf(v2.z); p1[3] = (short)f2bf(v2.w);
        p1[4] = (short)f2bf(v3.x); p1[5] = (short)f2bf(v3.y);
        p1[6] = (short)f2bf(v3.z); p1[7] = (short)f2bf(v3.w);
        if (k0 + 32 < IN_DIM && rowok) {
            v0 = *(const float4*)(xrow + k0 + 32 + 0);
            v1 = *(const float4*)(xrow + k0 + 32 + 4);
            v2 = *(const float4*)(xrow + k0 + 32 + 8);
            v3 = *(const float4*)(xrow + k0 + 32 + 12);
        }
        __syncthreads();
        *(bf16x8*)(Asl + sr * 40 + sch * 16 + 0) = p0;
        *(bf16x8*)(Asl + sr * 40 + sch * 16 + 8) = p1;
        __syncthreads();

        bf16x8 af[4], bfr[4];
#pragma unroll
        for (int i = 0; i < 4; ++i)
            af[i] = *(const bf16x8*)(Asl + (wm + i * 16 + mr) * 40 + ks * 8);
#pragma unroll
        for (int j = 0; j < 4; ++j)
            bfr[j] = *(const bf16x8*)(W1T + (size_t)(wn + j * 16 + mr) * IN_DIM + k0 + ks * 8);
#pragma unroll
        for (int i = 0; i < 4; ++i)
#pragma unroll
            for (int j = 0; j < 4; ++j)
                acc[i][j] = __builtin_amdgcn_mfma_f32_16x16x32_bf16(af[i], bfr[j], acc[i][j], 0, 0, 0);
    }

    // store h1b; D layout: col = wn + j*16 + mr, row = brow + wm + i*16 + ks*4 + r
#pragma unroll
    for (int i = 0; i < 4; ++i) {
#pragma unroll
        for (int j = 0; j < 4; ++j) {
            int col = wn + j * 16 + mr;
#pragma unroll
            for (int r = 0; r < 4; ++r) {
                int row = brow + wm + i * 16 + ks * 4 + r;
                if (row < NNODES) h1b[(size_t)row * HID + col] = f2bf(acc[i][j][r]);
            }
        }
    }

    // fused attention scores: head h_j = wn/16 + j owns cols wn+j*16+0..15;
    // el1[row*8+h_j] = sum_mr acc[i][j][r] * al1[wn+j*16+mr]  (xor-reduce over mr)
#pragma unroll
    for (int j = 0; j < 4; ++j) {
        const float alv = al1[wn + j * 16 + mr];
        const float arv = ar1[wn + j * 16 + mr];
        float pl[4][4], pr[4][4];
#pragma unroll
        for (int i = 0; i < 4; ++i)
#pragma unroll
            for (int r = 0; r < 4; ++r) {
                pl[i][r] = acc[i][j][r] * alv;
                pr[i][r] = acc[i][j][r] * arv;
            }
#pragma unroll
        for (int d = 1; d <= 8; d <<= 1) {
#pragma unroll
            for (int i = 0; i < 4; ++i)
#pragma unroll
                for (int r = 0; r < 4; ++r) {
                    pl[i][r] += __shfl_xor(pl[i][r], d, 64);
                    pr[i][r] += __shfl_xor(pr[i][r], d, 64);
                }
        }
        if (mr == 0) {
            const int hj = (wn >> 4) + j;
#pragma unroll
            for (int i = 0; i < 4; ++i)
#pragma unroll
                for (int r = 0; r < 4; ++r) {
                    int row = brow + wm + i * 16 + ks * 4 + r;
                    if (row < NNODES) {
                        el1[row * HEADS + hj] = pl[i][r];
                        er1[row * HEADS + hj] = pr[i][r];
                    }
                }
        }
    }
}

// ---------------- bf16 MFMA GEMM2: h2b = hf @ W2, fused el2/er2 ----------------
__global__ __launch_bounds__(256) void gemm2_kernel(const unsigned short* __restrict__ hfb,
                                                    const short* __restrict__ W2T,
                                                    const float* __restrict__ al2,
                                                    const float* __restrict__ ar2,
                                                    unsigned short* __restrict__ h2b,
                                                    float* __restrict__ el2,
                                                    float* __restrict__ er2) {
    __shared__ short A[128 * 136];
    const int tid = threadIdx.x;
    const int brow = blockIdx.x * 128;
    {
        int r = tid >> 1, half = tid & 1;
        int grow = brow + r;
        uint4* lp = (uint4*)(A + r * 136 + half * 64);
        if (grow < NNODES) {
            const uint4* gp = (const uint4*)(hfb + (size_t)grow * HID + half * 64);
#pragma unroll
            for (int i = 0; i < 8; ++i) lp[i] = gp[i];
        } else {
            uint4 z = {0, 0, 0, 0};
#pragma unroll
            for (int i = 0; i < 8; ++i) lp[i] = z;
        }
    }
    __syncthreads();

    const int wid = tid >> 6, lane = tid & 63;
    const int mr = lane & 15, ks = lane >> 4;
    const int wrow = wid * 32;

    f32x4 acc[2][4];
#pragma unroll
    for (int i = 0; i < 2; ++i)
#pragma unroll
        for (int j = 0; j < 4; ++j) acc[i][j] = (f32x4){0.f, 0.f, 0.f, 0.f};

#pragma unroll
    for (int kk = 0; kk < 4; ++kk) {
        const int k0 = kk * 32;
        bf16x8 af[2], bfr[4];
#pragma unroll
        for (int i = 0; i < 2; ++i)
            af[i] = *(const bf16x8*)(A + (wrow + i * 16 + mr) * 136 + k0 + ks * 8);
#pragma unroll
        for (int j = 0; j < 4; ++j)
            bfr[j] = *(const bf16x8*)(W2T + (size_t)(j * 16 + mr) * HID + k0 + ks * 8);
#pragma unroll
        for (int i = 0; i < 2; ++i)
#pragma unroll
            for (int j = 0; j < 4; ++j)
                acc[i][j] = __builtin_amdgcn_mfma_f32_16x16x32_bf16(af[i], bfr[j], acc[i][j], 0, 0, 0);
    }

    float al2v[4], ar2v[4];
#pragma unroll
    for (int j = 0; j < 4; ++j) { al2v[j] = al2[j * 16 + mr]; ar2v[j] = ar2[j * 16 + mr]; }

    float pl[2][4] = {}, pr[2][4] = {};
#pragma unroll
    for (int i = 0; i < 2; ++i) {
#pragma unroll
        for (int j = 0; j < 4; ++j) {
#pragma unroll
            for (int r = 0; r < 4; ++r) {
                float vvv = acc[i][j][r];
                pl[i][r] = fmaf(vvv, al2v[j], pl[i][r]);
                pr[i][r] = fmaf(vvv, ar2v[j], pr[i][r]);
                int row = brow + wrow + i * 16 + ks * 4 + r;
                if (row < NNODES) h2b[(size_t)row * NCLS + j * 16 + mr] = f2bf(vvv);
            }
        }
    }
#pragma unroll
    for (int d = 1; d <= 8; d <<= 1) {
#pragma unroll
        for (int i = 0; i < 2; ++i)
#pragma unroll
            for (int r = 0; r < 4; ++r) {
                pl[i][r] += __shfl_xor(pl[i][r], d, 64);
                pr[i][r] += __shfl_xor(pr[i][r], d, 64);
            }
    }
    if (mr == 0) {
#pragma unroll
        for (int i = 0; i < 2; ++i)
#pragma unroll
            for (int r = 0; r < 4; ++r) {
                int row = brow + wrow + i * 16 + ks * 4 + r;
                if (row < NNODES) { el2[row] = pl[i][r]; er2[row] = pr[i][r]; }
            }
    }
}

// ================= bucketized CSR build (packed u32 pairs) =================
__global__ __launch_bounds__(256) void bucket_hist_kernel(const int* __restrict__ dst,
                                                          int* __restrict__ gbcnt) {
    __shared__ int cnt[NBUCK];
    const int tid = threadIdx.x;
    for (int i = tid; i < NBUCK; i += 256) cnt[i] = 0;
    __syncthreads();
    const int base = blockIdx.x * EPB;
    for (int i = tid; i < EPB; i += 256) atomicAdd(&cnt[dst[base + i] >> 8], 1);
    __syncthreads();
    for (int i = tid; i < NBUCK; i += 256)
        if (cnt[i]) atomicAdd(&gbcnt[i], cnt[i]);
}

__global__ __launch_bounds__(512) void bucket_scan_kernel(const int* __restrict__ gbcnt,
                                                          int* __restrict__ bbase,
                                                          int* __restrict__ gcur) {
    __shared__ int buf[512];
    const int t = threadIdx.x;
    buf[t] = (t < NBUCK) ? gbcnt[t] : 0;
    __syncthreads();
#pragma unroll
    for (int d = 1; d < 512; d <<= 1) {
        int v = (t >= d) ? buf[t - d] : 0;
        __syncthreads();
        buf[t] += v;
        __syncthreads();
    }
    if (t < NBUCK) {
        int excl = (t == 0) ? 0 : buf[t - 1];
        bbase[t] = excl;
        gcur[t] = excl;
    }
    if (t == 0) bbase[NBUCK] = NEDGES;
}

__global__ __launch_bounds__(256) void bucket_scatter_kernel(const int* __restrict__ src,
                                                             const int* __restrict__ dst,
                                                             int* __restrict__ gcur,
                                                             unsigned* __restrict__ pairs) {
    __shared__ int cnt[NBUCK];
    __shared__ int base[NBUCK];
    const int tid = threadIdx.x;
    for (int i = tid; i < NBUCK; i += 256) cnt[i] = 0;
    __syncthreads();
    const int eb = blockIdx.x * EPB;
    for (int i = tid; i < EPB; i += 256) atomicAdd(&cnt[dst[eb + i] >> 8], 1);
    __syncthreads();
    for (int b = tid; b < NBUCK; b += 256) {
        int c = cnt[b];
        base[b] = c ? atomicAdd(&gcur[b], c) : 0;
        cnt[b] = 0;   // becomes cursor
    }
    __syncthreads();
    for (int i = tid; i < EPB; i += 256) {
        int d = dst[eb + i], s = src[eb + i];
        int b = d >> 8;
        int p = base[b] + atomicAdd(&cnt[b], 1);
        pairs[p] = ((unsigned)(d & 255) << 24) | (unsigned)s;   // src < 2^24
    }
}

__global__ __launch_bounds__(256) void bucket_csr_kernel(const unsigned* __restrict__ pairs,
                                                         const int* __restrict__ bbase,
                                                         int* __restrict__ row_off,
                                                         int* __restrict__ sorted_src) {
    __shared__ int ncnt[256];
    __shared__ int nbase[256];
    __shared__ int ws[4];
    const int tid = threadIdx.x, lane = tid & 63, wid = tid >> 6;
    const int b = blockIdx.x;
    const int nbeg = b << 8;
    const int ebeg = bbase[b], eend = bbase[b + 1];

    ncnt[tid] = 0;
    __syncthreads();
    for (int pos = ebeg + tid; pos < eend; pos += 256)
        atomicAdd(&ncnt[pairs[pos] >> 24], 1);
    __syncthreads();
    int v = ncnt[tid];
    int x = v;
#pragma unroll
    for (int d = 1; d < 64; d <<= 1) {
        int y = __shfl_up(x, d, 64);
        if (lane >= d) x += y;
    }
    if (lane == 63) ws[wid] = x;
    __syncthreads();
    int woff = 0;
#pragma unroll
    for (int i = 0; i < 4; ++i) if (i < wid) woff += ws[i];
    int gb = ebeg + woff + (x - v);
    int node = nbeg + tid;
    if (node < NNODES) row_off[node] = gb;
    nbase[tid] = gb;
    ncnt[tid] = 0;   // becomes cursor
    __syncthreads();
    for (int pos = ebeg + tid; pos < eend; pos += 256) {
        unsigned pr = pairs[pos];
        int l = pr >> 24;
        int p = nbase[l] + atomicAdd(&ncnt[l], 1);
        sorted_src[p] = (int)(pr & 0xFFFFFFu);
    }
    if (b == 0 && tid == 0) row_off[NNODES] = NEDGES;
}

// ---------------- layer-1 aggregation: inline scores, 4 groups x 16 lanes ----------------
__global__ __launch_bounds__(256) void aggregate1_kernel(const unsigned short* __restrict__ h1b,
                                                         const float* __restrict__ el1,
                                                         const float* __restrict__ er1,
                                                         const int* __restrict__ row_off,
                                                         const int* __restrict__ sorted_src,
                                                         const float* __restrict__ b1,
                                                         unsigned short* __restrict__ hfb) {
    __shared__ float b1s[HID];
    const int tid = threadIdx.x;
    if (tid < HID) b1s[tid] = b1[tid];
    __syncthreads();

    const int wid = tid >> 6, lane = tid & 63;
    const int g = lane >> 4, sub = lane & 15, hd = sub >> 1;

    for (int v = blockIdx.x * 4 + wid; v < NNODES; v += gridDim.x * 4) {
        const int beg = row_off[v], end = row_off[v + 1];
        const float er_v = er1[v * HEADS + hd];
        float a[8] = {0.f, 0.f, 0.f, 0.f, 0.f, 0.f, 0.f, 0.f};
        float sp = 0.f;
        for (int j0 = beg; j0 < end; j0 += 64) {
            const int nj = min(64, end - j0);
            const int nit = (nj + 3) >> 2;
            int us = (j0 + lane < end) ? sorted_src[j0 + lane] : 0;
            for (int ib = 0; ib < nit; ib += 4) {
                int j0i = g + 4 * (ib + 0), j1i = g + 4 * (ib + 1);
                int j2i = g + 4 * (ib + 2), j3i = g + 4 * (ib + 3);
                int u0 = __shfl(us, j0i, 64);
                int u1 = __shfl(us, j1i, 64);
                int u2 = __shfl(us, j2i, 64);
                int u3 = __shfl(us, j3i, 64);
                uint4 w0 = *(const uint4*)(h1b + ((unsigned)(u0 << 7) + sub * 8));
                uint4 w1 = *(const uint4*)(h1b + ((unsigned)(u1 << 7) + sub * 8));
                uint4 w2 = *(const uint4*)(h1b + ((unsigned)(u2 << 7) + sub * 8));
                uint4 w3 = *(const uint4*)(h1b + ((unsigned)(u3 << 7) + sub * 8));
                float e0 = el1[(unsigned)(u0 << 3) + hd];
                float e1 = el1[(unsigned)(u1 << 3) + hd];
                float e2 = el1[(unsigned)(u2 << 3) + hd];
                float e3 = el1[(unsigned)(u3 << 3) + hd];
                float s0 = e0 + er_v; s0 = s0 > 0.f ? s0 : SLOPE * s0;
                float s1 = e1 + er_v; s1 = s1 > 0.f ? s1 : SLOPE * s1;
                float s2 = e2 + er_v; s2 = s2 > 0.f ? s2 : SLOPE * s2;
                float s3 = e3 + er_v; s3 = s3 > 0.f ? s3 : SLOPE * s3;
                float p0 = (j0i < nj) ? __expf(s0) : 0.f;
                float p1 = (j1i < nj) ? __expf(s1) : 0.f;
                float p2 = (j2i < nj) ? __expf(s2) : 0.f;
                float p3 = (j3i < nj) ? __expf(s3) : 0.f;
                sp += p0 + p1 + p2 + p3;
#define ACC8(P, W) \
                a[0] = fmaf(P, bflo(W.x), a[0]); a[1] = fmaf(P, bfhi(W.x), a[1]); \
                a[2] = fmaf(P, bflo(W.y), a[2]); a[3] = fmaf(P, bfhi(W.y), a[3]); \
                a[4] = fmaf(P, bflo(W.z), a[4]); a[5] = fmaf(P, bfhi(W.z), a[5]); \
                a[6] = fmaf(P, bflo(W.w), a[6]); a[7] = fmaf(P, bfhi(W.w), a[7]);
                ACC8(p0, w0) ACC8(p1, w1) ACC8(p2, w2) ACC8(p3, w3)
#undef ACC8
            }
        }
#pragma unroll
        for (int d = 16; d <= 32; d <<= 1) {
#pragma unroll
            for (int i = 0; i < 8; ++i) a[i] += __shfl_xor(a[i], d, 64);
            sp += __shfl_xor(sp, d, 64);
        }
        float inv = sp > 0.f ? 1.0f / sp : 0.f;
        float f[8];
#pragma unroll
        for (int i = 0; i < 8; ++i) {
            float t = a[i] * inv + b1s[sub * 8 + i];
            t = t > 0.f ? t : __expf(t) - 1.f;   // ELU via hw exp
            t = t > 0.f ? t : __expf(t) - 1.f;
            f[i] = t;
        }
        if (g == 0) {
            uint4 w;
            w.x = (unsigned)f2bf(f[0]) | ((unsigned)f2bf(f[1]) << 16);
            w.y = (unsigned)f2bf(f[2]) | ((unsigned)f2bf(f[3]) << 16);
            w.z = (unsigned)f2bf(f[4]) | ((unsigned)f2bf(f[5]) << 16);
            w.w = (unsigned)f2bf(f[6]) | ((unsigned)f2bf(f[7]) << 16);
            *(uint4*)(hfb + (size_t)v * HID + sub * 8) = w;
        }
    }
}

// ---------------- layer-2 aggregation: inline scores, 8 groups x 8 lanes ----------------
__global__ __launch_bounds__(256) void aggregate2_kernel(const unsigned short* __restrict__ h2b,
                                                         const float* __restrict__ el2,
                                                         const float* __restrict__ er2,
                                                         const int* __restrict__ row_off,
                                                         const int* __restrict__ sorted_src,
                                                         const float* __restrict__ b2,
                                                         float* __restrict__ out) {
    const int tid = threadIdx.x;
    const int v = blockIdx.x * 4 + (tid >> 6);
    if (v >= NNODES) return;
    const int lane = tid & 63, g = lane >> 3, sub = lane & 7;
    const int beg = row_off[v], end = row_off[v + 1];
    const float er_v = er2[v];
    float a[8] = {0.f, 0.f, 0.f, 0.f, 0.f, 0.f, 0.f, 0.f};
    float sp = 0.f;
    for (int j0 = beg; j0 < end; j0 += 64) {
        const int nj = min(64, end - j0);
        const int nit = (nj + 7) >> 3;
        bool valid = j0 + lane < end;
        int us = valid ? sorted_src[j0 + lane] : 0;
        float ev = valid ? el2[us] : 0.f;
        for (int ib = 0; ib < nit; ib += 4) {
            int j0i = g + 8 * (ib + 0), j1i = g + 8 * (ib + 1);
            int j2i = g + 8 * (ib + 2), j3i = g + 8 * (ib + 3);
            int u0 = __shfl(us, j0i, 64);
            int u1 = __shfl(us, j1i, 64);
            int u2 = __shfl(us, j2i, 64);
            int u3 = __shfl(us, j3i, 64);
            float s0 = __shfl(ev, j0i, 64) + er_v; s0 = s0 > 0.f ? s0 : SLOPE * s0;
            float s1 = __shfl(ev, j1i, 64) + er_v; s1 = s1 > 0.f ? s1 : SLOPE * s1;
            float s2 = __shfl(ev, j2i, 64) + er_v; s2 = s2 > 0.f ? s2 : SLOPE * s2;
            float s3 = __shfl(ev, j3i, 64) + er_v; s3 = s3 > 0.f ? s3 : SLOPE * s3;
            float p0 = (j0i < nj) ? __expf(s0) : 0.f;
            float p1 = (j1i < nj) ? __expf(s1) : 0.f;
            float p2 = (j2i < nj) ? __expf(s2) : 0.f;
            float p3 = (j3i < nj) ? __expf(s3) : 0.f;
            uint4 w0 = *(const uint4*)(h2b + ((unsigned)(u0 << 6) + sub * 8));
            uint4 w1 = *(const uint4*)(h2b + ((unsigned)(u1 << 6) + sub * 8));
            uint4 w2 = *(const uint4*)(h2b + ((unsigned)(u2 << 6) + sub * 8));
            uint4 w3 = *(const uint4*)(h2b + ((unsigned)(u3 << 6) + sub * 8));
            sp += p0 + p1 + p2 + p3;
#define ACC8(P, W) \
            a[0] = fmaf(P, bflo(W.x), a[0]); a[1] = fmaf(P, bfhi(W.x), a[1]); \
            a[2] = fmaf(P, bflo(W.y), a[2]); a[3] = fmaf(P, bfhi(W.y), a[3]); \
            a[4] = fmaf(P, bflo(W.z), a[4]); a[5] = fmaf(P, bfhi(W.z), a[5]); \
            a[6] = fmaf(P, bflo(W.w), a[6]); a[7] = fmaf(P, bfhi(W.w), a[7]);
            ACC8(p0, w0) ACC8(p1, w1) ACC8(p2, w2) ACC8(p3, w3)
#undef ACC8
        }
    }
#pragma unroll
    for (int d = 8; d <= 32; d <<= 1) {
#pragma unroll
        for (int i = 0; i < 8; ++i) a[i] += __shfl_xor(a[i], d, 64);
        sp += __shfl_xor(sp, d, 64);
    }
    if (g == 0) {
        float inv = sp > 0.f ? 1.0f / sp : 0.f;
        float4 b0 = *(const float4*)(b2 + sub * 8);
        float4 b1v = *(const float4*)(b2 + sub * 8 + 4);
        float4 o0, o1;
        o0.x = a[0] * inv + b0.x; o0.y = a[1] * inv + b0.y;
        o0.z = a[2] * inv + b0.z; o0.w = a[3] * inv + b0.w;
        o1.x = a[4] * inv + b1v.x; o1.y = a[5] * inv + b1v.y;
        o1.z = a[6] * inv + b1v.z; o1.w = a[7] * inv + b1v.w;
        *(float4*)(out + (size_t)v * NCLS + sub * 8) = o0;
        *(float4*)(out + (size_t)v * NCLS + sub * 8 + 4) = o1;
    }
}

extern "C" void kernel_launch(void* const* d_in, const int* in_sizes, int n_in,
                              void* d_out, int out_size, void* d_ws, size_t ws_size,
                              hipStream_t stream) {
    const float* x   = (const float*)d_in[0];
    const int*   src = (const int*)d_in[1];
    const int*   dst = (const int*)d_in[2];
    const float* W1  = (const float*)d_in[3];
    const float* al1 = (const float*)d_in[4];
    const float* ar1 = (const float*)d_in[5];
    const float* b1  = (const float*)d_in[6];
    const float* W2  = (const float*)d_in[7];
    const float* al2 = (const float*)d_in[8];
    const float* ar2 = (const float*)d_in[9];
    const float* b2  = (const float*)d_in[10];
    float* out = (float*)d_out;

    // workspace layout (~85 MB)
    float* el1 = (float*)d_ws;                                 // N*HEADS f32
    float* er1 = el1 + (size_t)NNODES * HEADS;
    float* el2 = er1 + (size_t)NNODES * HEADS;                 // N
    float* er2 = el2 + NNODES;
    unsigned short* h1b = (unsigned short*)(er2 + NNODES);     // N*HID bf16
    unsigned short* hfb = h1b + (size_t)NNODES * HID;          // N*HID bf16
    unsigned short* h2b = hfb + (size_t)NNODES * HID;          // N*NCLS bf16
    int* row_off    = (int*)(h2b + (size_t)NNODES * NCLS);     // N+1 (+pad)
    int* sorted_src = row_off + NNODES + 4;                    // E
    short* W1T      = (short*)(sorted_src + NEDGES);           // HID*IN_DIM bf16
    short* W2T      = W1T + (size_t)HID * IN_DIM;              // NCLS*HID bf16
    int* gbcnt      = (int*)(W2T + (size_t)NCLS * HID);        // NBUCK
    int* bbase      = gbcnt + NBUCK;                           // NBUCK+1
    int* gcur       = bbase + NBUCK + 1;                       // NBUCK
    unsigned* pairs = (unsigned*)(gcur + NBUCK);               // E packed u32

    // ---- bucketized CSR build ----
    hipMemsetAsync(gbcnt, 0, NBUCK * sizeof(int), stream);
    bucket_hist_kernel<<<NBBLK, 256, 0, stream>>>(dst, gbcnt);
    bucket_scan_kernel<<<1, 512, 0, stream>>>(gbcnt, bbase, gcur);
    bucket_scatter_kernel<<<NBBLK, 256, 0, stream>>>(src, dst, gcur, pairs);
    bucket_csr_kernel<<<NBUCK, 256, 0, stream>>>(pairs, bbase, row_off, sorted_src);

    // ---- layer 1 ----
    prep_w1t_kernel<<<(IN_DIM * HID + 255) / 256, 256, 0, stream>>>(W1, W1T);
    prep_w2t_kernel<<<(HID * NCLS + 255) / 256, 256, 0, stream>>>(W2, W2T);
    gemm1_kernel<<<(NNODES + 127) / 128, 256, 0, stream>>>(x, W1T, al1, ar1, h1b, el1, er1);
    aggregate1_kernel<<<2048, 256, 0, stream>>>(h1b, el1, er1, row_off, sorted_src, b1, hfb);

    // ---- layer 2 ----
    gemm2_kernel<<<(NNODES + 127) / 128, 256, 0, stream>>>(hfb, W2T, al2, ar2, h2b, el2, er2);
    aggregate2_kernel<<<(NNODES + 3) / 4, 256, 0, stream>>>(h2b, el2, er2, row_off, sorted_src,
                                                            b2, out);
}

// Round 13
// 260.996 us; speedup vs baseline: 1.2026x; 1.2026x over previous
//
#include <hip/hip_runtime.h>
#include <hip/hip_bf16.h>
#include <cstdint>
#include <cstddef>

#define NNODES 100000
#define NEDGES 1600000
#define IN_DIM 256
#define HID 128
#define HEADS 8
#define DH 16
#define NCLS 64
#define SLOPE 0.2f

#define NBUCK 391              // (NNODES+255)>>8, 256 nodes per bucket
#define BCAP 5120              // fixed bucket capacity (Poisson mean 4092, +16 sigma)
#define EPB 4000               // edges per block in scatter pass (400*4000 = E)
#define NBBLK 400

typedef __attribute__((ext_vector_type(8))) short bf16x8;
typedef __attribute__((ext_vector_type(4))) float f32x4;

static __device__ __forceinline__ unsigned short f2bf(float f) {
    __hip_bfloat16 h = __float2bfloat16(f);
    unsigned short r;
    __builtin_memcpy(&r, &h, sizeof(r));
    return r;
}
static __device__ __forceinline__ float bflo(unsigned int w) {
    union { uint32_t u; float f; } c; c.u = w << 16; return c.f;
}
static __device__ __forceinline__ float bfhi(unsigned int w) {
    union { uint32_t u; float f; } c; c.u = w & 0xFFFF0000u; return c.f;
}

// ---------------- W1 -> W1T bf16 [HID][IN_DIM] ----------------
__global__ __launch_bounds__(256) void prep_w1t_kernel(const float* __restrict__ W1,
                                                       short* __restrict__ W1T) {
    int idx = blockIdx.x * 256 + threadIdx.x;
    if (idx >= IN_DIM * HID) return;
    int k = idx >> 7;
    int n = idx & 127;
    W1T[n * IN_DIM + k] = (short)f2bf(W1[idx]);
}

// ---------------- W2 -> W2T bf16 [NCLS][HID] ----------------
__global__ __launch_bounds__(256) void prep_w2t_kernel(const float* __restrict__ W2,
                                                       short* __restrict__ W2T) {
    int idx = blockIdx.x * 256 + threadIdx.x;
    if (idx >= HID * NCLS) return;
    int k = idx >> 6;
    int n = idx & 63;
    W2T[n * HID + k] = (short)f2bf(W2[idx]);
}

// ---------------- bf16 MFMA GEMM1: h1b[M,128](bf16) = x[M,256] @ W1 ----------------
__global__ __launch_bounds__(256) void gemm1_kernel(const float* __restrict__ x,
                                                    const short* __restrict__ W1T,
                                                    unsigned short* __restrict__ h1b) {
    __shared__ short Asl[128 * 40];
    const int tid = threadIdx.x;
    const int brow = blockIdx.x * 128;
    const int wid = tid >> 6, lane = tid & 63;
    const int wm = (wid >> 1) * 64, wn = (wid & 1) * 64;
    const int mr = lane & 15;
    const int ks = lane >> 4;
    const int sr = tid >> 1;
    const int sch = tid & 1;
    const int grow = brow + sr;
    const bool rowok = grow < NNODES;
    const float* xrow = x + (size_t)grow * IN_DIM + sch * 16;

    f32x4 acc[4][4];
#pragma unroll
    for (int i = 0; i < 4; ++i)
#pragma unroll
        for (int j = 0; j < 4; ++j) acc[i][j] = (f32x4){0.f, 0.f, 0.f, 0.f};

    float4 v0 = {0,0,0,0}, v1 = {0,0,0,0}, v2 = {0,0,0,0}, v3 = {0,0,0,0};
    if (rowok) {
        v0 = *(const float4*)(xrow + 0);
        v1 = *(const float4*)(xrow + 4);
        v2 = *(const float4*)(xrow + 8);
        v3 = *(const float4*)(xrow + 12);
    }

    for (int k0 = 0; k0 < IN_DIM; k0 += 32) {
        bf16x8 p0, p1;
        p0[0] = (short)f2bf(v0.x); p0[1] = (short)f2bf(v0.y);
        p0[2] = (short)f2bf(v0.z); p0[3] = (short)f2bf(v0.w);
        p0[4] = (short)f2bf(v1.x); p0[5] = (short)f2bf(v1.y);
        p0[6] = (short)f2bf(v1.z); p0[7] = (short)f2bf(v1.w);
        p1[0] = (short)f2bf(v2.x); p1[1] = (short)f2bf(v2.y);
        p1[2] = (short)f2bf(v2.z); p1[3] = (short)f2bf(v2.w);
        p1[4] = (short)f2bf(v3.x); p1[5] = (short)f2bf(v3.y);
        p1[6] = (short)f2bf(v3.z); p1[7] = (short)f2bf(v3.w);
        if (k0 + 32 < IN_DIM && rowok) {
            v0 = *(const float4*)(xrow + k0 + 32 + 0);
            v1 = *(const float4*)(xrow + k0 + 32 + 4);
            v2 = *(const float4*)(xrow + k0 + 32 + 8);
            v3 = *(const float4*)(xrow + k0 + 32 + 12);
        }
        __syncthreads();
        *(bf16x8*)(Asl + sr * 40 + sch * 16 + 0) = p0;
        *(bf16x8*)(Asl + sr * 40 + sch * 16 + 8) = p1;
        __syncthreads();

        bf16x8 af[4], bfr[4];
#pragma unroll
        for (int i = 0; i < 4; ++i)
            af[i] = *(const bf16x8*)(Asl + (wm + i * 16 + mr) * 40 + ks * 8);
#pragma unroll
        for (int j = 0; j < 4; ++j)
            bfr[j] = *(const bf16x8*)(W1T + (size_t)(wn + j * 16 + mr) * IN_DIM + k0 + ks * 8);
#pragma unroll
        for (int i = 0; i < 4; ++i)
#pragma unroll
            for (int j = 0; j < 4; ++j)
                acc[i][j] = __builtin_amdgcn_mfma_f32_16x16x32_bf16(af[i], bfr[j], acc[i][j], 0, 0, 0);
    }

#pragma unroll
    for (int i = 0; i < 4; ++i) {
#pragma unroll
        for (int j = 0; j < 4; ++j) {
            int col = wn + j * 16 + mr;
#pragma unroll
            for (int r = 0; r < 4; ++r) {
                int row = brow + wm + i * 16 + ks * 4 + r;
                if (row < NNODES) h1b[(size_t)row * HID + col] = f2bf(acc[i][j][r]);
            }
        }
    }
}

// ---------------- bf16 MFMA GEMM2: h2b = hf @ W2, fused el2/er2 ----------------
__global__ __launch_bounds__(256) void gemm2_kernel(const unsigned short* __restrict__ hfb,
                                                    const short* __restrict__ W2T,
                                                    const float* __restrict__ al2,
                                                    const float* __restrict__ ar2,
                                                    unsigned short* __restrict__ h2b,
                                                    float* __restrict__ el2,
                                                    float* __restrict__ er2) {
    __shared__ short A[128 * 136];
    const int tid = threadIdx.x;
    const int brow = blockIdx.x * 128;
    {
        int r = tid >> 1, half = tid & 1;
        int grow = brow + r;
        uint4* lp = (uint4*)(A + r * 136 + half * 64);
        if (grow < NNODES) {
            const uint4* gp = (const uint4*)(hfb + (size_t)grow * HID + half * 64);
#pragma unroll
            for (int i = 0; i < 8; ++i) lp[i] = gp[i];
        } else {
            uint4 z = {0, 0, 0, 0};
#pragma unroll
            for (int i = 0; i < 8; ++i) lp[i] = z;
        }
    }
    __syncthreads();

    const int wid = tid >> 6, lane = tid & 63;
    const int mr = lane & 15, ks = lane >> 4;
    const int wrow = wid * 32;

    f32x4 acc[2][4];
#pragma unroll
    for (int i = 0; i < 2; ++i)
#pragma unroll
        for (int j = 0; j < 4; ++j) acc[i][j] = (f32x4){0.f, 0.f, 0.f, 0.f};

#pragma unroll
    for (int kk = 0; kk < 4; ++kk) {
        const int k0 = kk * 32;
        bf16x8 af[2], bfr[4];
#pragma unroll
        for (int i = 0; i < 2; ++i)
            af[i] = *(const bf16x8*)(A + (wrow + i * 16 + mr) * 136 + k0 + ks * 8);
#pragma unroll
        for (int j = 0; j < 4; ++j)
            bfr[j] = *(const bf16x8*)(W2T + (size_t)(j * 16 + mr) * HID + k0 + ks * 8);
#pragma unroll
        for (int i = 0; i < 2; ++i)
#pragma unroll
            for (int j = 0; j < 4; ++j)
                acc[i][j] = __builtin_amdgcn_mfma_f32_16x16x32_bf16(af[i], bfr[j], acc[i][j], 0, 0, 0);
    }

    float al2v[4], ar2v[4];
#pragma unroll
    for (int j = 0; j < 4; ++j) { al2v[j] = al2[j * 16 + mr]; ar2v[j] = ar2[j * 16 + mr]; }

    float pl[2][4] = {}, pr[2][4] = {};
#pragma unroll
    for (int i = 0; i < 2; ++i) {
#pragma unroll
        for (int j = 0; j < 4; ++j) {
#pragma unroll
            for (int r = 0; r < 4; ++r) {
                float vvv = acc[i][j][r];
                pl[i][r] = fmaf(vvv, al2v[j], pl[i][r]);
                pr[i][r] = fmaf(vvv, ar2v[j], pr[i][r]);
                int row = brow + wrow + i * 16 + ks * 4 + r;
                if (row < NNODES) h2b[(size_t)row * NCLS + j * 16 + mr] = f2bf(vvv);
            }
        }
    }
#pragma unroll
    for (int d = 1; d <= 8; d <<= 1) {
#pragma unroll
        for (int i = 0; i < 2; ++i)
#pragma unroll
            for (int r = 0; r < 4; ++r) {
                pl[i][r] += __shfl_xor(pl[i][r], d, 64);
                pr[i][r] += __shfl_xor(pr[i][r], d, 64);
            }
    }
    if (mr == 0) {
#pragma unroll
        for (int i = 0; i < 2; ++i)
#pragma unroll
            for (int r = 0; r < 4; ++r) {
                int row = brow + wrow + i * 16 + ks * 4 + r;
                if (row < NNODES) { el2[row] = pl[i][r]; er2[row] = pr[i][r]; }
            }
    }
}

// ================= bucketized CSR build, fixed-capacity (no hist/scan) =================
__global__ __launch_bounds__(256) void init_gcur_kernel(int* __restrict__ gcur) {
    int b = blockIdx.x * 256 + threadIdx.x;
    if (b < NBUCK) gcur[b] = b * BCAP;
}

__global__ __launch_bounds__(256) void bucket_scatter_kernel(const int* __restrict__ src,
                                                             const int* __restrict__ dst,
                                                             int* __restrict__ gcur,
                                                             unsigned* __restrict__ pairs) {
    __shared__ int cnt[NBUCK];
    __shared__ int base[NBUCK];
    const int tid = threadIdx.x;
    for (int i = tid; i < NBUCK; i += 256) cnt[i] = 0;
    __syncthreads();
    const int eb = blockIdx.x * EPB;
    for (int i = tid; i < EPB; i += 256) atomicAdd(&cnt[dst[eb + i] >> 8], 1);
    __syncthreads();
    for (int b = tid; b < NBUCK; b += 256) {
        int c = cnt[b];
        base[b] = c ? atomicAdd(&gcur[b], c) : 0;
        cnt[b] = 0;   // becomes cursor
    }
    __syncthreads();
    for (int i = tid; i < EPB; i += 256) {
        int d = dst[eb + i], s = src[eb + i];
        int b = d >> 8;
        int p = base[b] + atomicAdd(&cnt[b], 1);
        pairs[p] = ((unsigned)(d & 255) << 24) | (unsigned)s;   // src < 2^24
    }
}

// per-bucket local CSR: row_off (gapped global positions) + row_cnt + sorted_src
__global__ __launch_bounds__(256) void bucket_csr_kernel(const unsigned* __restrict__ pairs,
                                                         const int* __restrict__ gcur,
                                                         int* __restrict__ row_off,
                                                         int* __restrict__ row_cnt,
                                                         int* __restrict__ sorted_src) {
    __shared__ int ncnt[256];
    __shared__ int nbase[256];
    __shared__ int ws[4];
    const int tid = threadIdx.x, lane = tid & 63, wid = tid >> 6;
    const int b = blockIdx.x;
    const int nbeg = b << 8;
    const int ebeg = b * BCAP;
    const int eend = gcur[b];        // ebeg + edges in this bucket

    ncnt[tid] = 0;
    __syncthreads();
    for (int pos = ebeg + tid; pos < eend; pos += 256)
        atomicAdd(&ncnt[pairs[pos] >> 24], 1);
    __syncthreads();
    int v = ncnt[tid];
    int x = v;
#pragma unroll
    for (int d = 1; d < 64; d <<= 1) {
        int y = __shfl_up(x, d, 64);
        if (lane >= d) x += y;
    }
    if (lane == 63) ws[wid] = x;
    __syncthreads();
    int woff = 0;
#pragma unroll
    for (int i = 0; i < 4; ++i) if (i < wid) woff += ws[i];
    int gb = ebeg + woff + (x - v);
    int node = nbeg + tid;
    if (node < NNODES) { row_off[node] = gb; row_cnt[node] = v; }
    nbase[tid] = gb;
    ncnt[tid] = 0;   // becomes cursor
    __syncthreads();
    for (int pos = ebeg + tid; pos < eend; pos += 256) {
        unsigned pr = pairs[pos];
        int l = pr >> 24;
        int p = nbase[l] + atomicAdd(&ncnt[l], 1);
        sorted_src[p] = (int)(pr & 0xFFFFFFu);
    }
}

// ---------------- layer-1 attention scores (bf16 h1 in) ----------------
__global__ __launch_bounds__(256) void attn_scores_kernel(const unsigned short* __restrict__ h1b,
                                                          const float* __restrict__ al,
                                                          const float* __restrict__ ar,
                                                          float* __restrict__ el,
                                                          float* __restrict__ er) {
    int idx = blockIdx.x * 256 + threadIdx.x;
    if (idx >= NNODES * HEADS) return;
    int hd = idx & (HEADS - 1);
    const uint4* hp = (const uint4*)(h1b + (size_t)idx * DH);
    uint4 A = hp[0], B = hp[1];
    unsigned int w[8] = {A.x, A.y, A.z, A.w, B.x, B.y, B.z, B.w};
    float a = 0.f, c = 0.f;
#pragma unroll
    for (int i = 0; i < 8; ++i) {
        float lo = bflo(w[i]), hi = bfhi(w[i]);
        a = fmaf(lo, al[hd * DH + 2 * i], a);
        a = fmaf(hi, al[hd * DH + 2 * i + 1], a);
        c = fmaf(lo, ar[hd * DH + 2 * i], c);
        c = fmaf(hi, ar[hd * DH + 2 * i + 1], c);
    }
    el[idx] = a;
    er[idx] = c;
}

// ---------------- layer-1 aggregation: inline scores, 4 groups x 16 lanes ----------------
__global__ __launch_bounds__(256) void aggregate1_kernel(const unsigned short* __restrict__ h1b,
                                                         const float* __restrict__ el1,
                                                         const float* __restrict__ er1,
                                                         const int* __restrict__ row_off,
                                                         const int* __restrict__ row_cnt,
                                                         const int* __restrict__ sorted_src,
                                                         const float* __restrict__ b1,
                                                         unsigned short* __restrict__ hfb) {
    __shared__ float b1s[HID];
    const int tid = threadIdx.x;
    if (tid < HID) b1s[tid] = b1[tid];
    __syncthreads();

    const int wid = tid >> 6, lane = tid & 63;
    const int g = lane >> 4, sub = lane & 15, hd = sub >> 1;

    for (int v = blockIdx.x * 4 + wid; v < NNODES; v += gridDim.x * 4) {
        const int beg = row_off[v];
        const int end = beg + row_cnt[v];
        const float er_v = er1[v * HEADS + hd];
        float a[8] = {0.f, 0.f, 0.f, 0.f, 0.f, 0.f, 0.f, 0.f};
        float sp = 0.f;
        for (int j0 = beg; j0 < end; j0 += 64) {
            const int nj = min(64, end - j0);
            const int nit = (nj + 3) >> 2;
            int us = (j0 + lane < end) ? sorted_src[j0 + lane] : 0;
            for (int ib = 0; ib < nit; ib += 4) {
                int j0i = g + 4 * (ib + 0), j1i = g + 4 * (ib + 1);
                int j2i = g + 4 * (ib + 2), j3i = g + 4 * (ib + 3);
                int u0 = __shfl(us, j0i, 64);
                int u1 = __shfl(us, j1i, 64);
                int u2 = __shfl(us, j2i, 64);
                int u3 = __shfl(us, j3i, 64);
                uint4 w0 = *(const uint4*)(h1b + ((unsigned)(u0 << 7) + sub * 8));
                uint4 w1 = *(const uint4*)(h1b + ((unsigned)(u1 << 7) + sub * 8));
                uint4 w2 = *(const uint4*)(h1b + ((unsigned)(u2 << 7) + sub * 8));
                uint4 w3 = *(const uint4*)(h1b + ((unsigned)(u3 << 7) + sub * 8));
                float e0 = el1[(unsigned)(u0 << 3) + hd];
                float e1 = el1[(unsigned)(u1 << 3) + hd];
                float e2 = el1[(unsigned)(u2 << 3) + hd];
                float e3 = el1[(unsigned)(u3 << 3) + hd];
                float s0 = e0 + er_v; s0 = s0 > 0.f ? s0 : SLOPE * s0;
                float s1 = e1 + er_v; s1 = s1 > 0.f ? s1 : SLOPE * s1;
                float s2 = e2 + er_v; s2 = s2 > 0.f ? s2 : SLOPE * s2;
                float s3 = e3 + er_v; s3 = s3 > 0.f ? s3 : SLOPE * s3;
                float p0 = (j0i < nj) ? __expf(s0) : 0.f;
                float p1 = (j1i < nj) ? __expf(s1) : 0.f;
                float p2 = (j2i < nj) ? __expf(s2) : 0.f;
                float p3 = (j3i < nj) ? __expf(s3) : 0.f;
                sp += p0 + p1 + p2 + p3;
#define ACC8(P, W) \
                a[0] = fmaf(P, bflo(W.x), a[0]); a[1] = fmaf(P, bfhi(W.x), a[1]); \
                a[2] = fmaf(P, bflo(W.y), a[2]); a[3] = fmaf(P, bfhi(W.y), a[3]); \
                a[4] = fmaf(P, bflo(W.z), a[4]); a[5] = fmaf(P, bfhi(W.z), a[5]); \
                a[6] = fmaf(P, bflo(W.w), a[6]); a[7] = fmaf(P, bfhi(W.w), a[7]);
                ACC8(p0, w0) ACC8(p1, w1) ACC8(p2, w2) ACC8(p3, w3)
#undef ACC8
            }
        }
#pragma unroll
        for (int d = 16; d <= 32; d <<= 1) {
#pragma unroll
            for (int i = 0; i < 8; ++i) a[i] += __shfl_xor(a[i], d, 64);
            sp += __shfl_xor(sp, d, 64);
        }
        float inv = sp > 0.f ? 1.0f / sp : 0.f;
        float f[8];
#pragma unroll
        for (int i = 0; i < 8; ++i) {
            float t = a[i] * inv + b1s[sub * 8 + i];
            t = t > 0.f ? t : __expf(t) - 1.f;   // ELU via hw exp
            t = t > 0.f ? t : __expf(t) - 1.f;
            f[i] = t;
        }
        if (g == 0) {
            uint4 w;
            w.x = (unsigned)f2bf(f[0]) | ((unsigned)f2bf(f[1]) << 16);
            w.y = (unsigned)f2bf(f[2]) | ((unsigned)f2bf(f[3]) << 16);
            w.z = (unsigned)f2bf(f[4]) | ((unsigned)f2bf(f[5]) << 16);
            w.w = (unsigned)f2bf(f[6]) | ((unsigned)f2bf(f[7]) << 16);
            *(uint4*)(hfb + (size_t)v * HID + sub * 8) = w;
        }
    }
}

// ---------------- layer-2 aggregation: inline scores, 8 groups x 8 lanes ----------------
__global__ __launch_bounds__(256) void aggregate2_kernel(const unsigned short* __restrict__ h2b,
                                                         const float* __restrict__ el2,
                                                         const float* __restrict__ er2,
                                                         const int* __restrict__ row_off,
                                                         const int* __restrict__ row_cnt,
                                                         const int* __restrict__ sorted_src,
                                                         const float* __restrict__ b2,
                                                         float* __restrict__ out) {
    const int tid = threadIdx.x;
    const int v = blockIdx.x * 4 + (tid >> 6);
    if (v >= NNODES) return;
    const int lane = tid & 63, g = lane >> 3, sub = lane & 7;
    const int beg = row_off[v];
    const int end = beg + row_cnt[v];
    const float er_v = er2[v];
    float a[8] = {0.f, 0.f, 0.f, 0.f, 0.f, 0.f, 0.f, 0.f};
    float sp = 0.f;
    for (int j0 = beg; j0 < end; j0 += 64) {
        const int nj = min(64, end - j0);
        const int nit = (nj + 7) >> 3;
        bool valid = j0 + lane < end;
        int us = valid ? sorted_src[j0 + lane] : 0;
        float ev = valid ? el2[us] : 0.f;
        for (int ib = 0; ib < nit; ib += 4) {
            int j0i = g + 8 * (ib + 0), j1i = g + 8 * (ib + 1);
            int j2i = g + 8 * (ib + 2), j3i = g + 8 * (ib + 3);
            int u0 = __shfl(us, j0i, 64);
            int u1 = __shfl(us, j1i, 64);
            int u2 = __shfl(us, j2i, 64);
            int u3 = __shfl(us, j3i, 64);
            float s0 = __shfl(ev, j0i, 64) + er_v; s0 = s0 > 0.f ? s0 : SLOPE * s0;
            float s1 = __shfl(ev, j1i, 64) + er_v; s1 = s1 > 0.f ? s1 : SLOPE * s1;
            float s2 = __shfl(ev, j2i, 64) + er_v; s2 = s2 > 0.f ? s2 : SLOPE * s2;
            float s3 = __shfl(ev, j3i, 64) + er_v; s3 = s3 > 0.f ? s3 : SLOPE * s3;
            float p0 = (j0i < nj) ? __expf(s0) : 0.f;
            float p1 = (j1i < nj) ? __expf(s1) : 0.f;
            float p2 = (j2i < nj) ? __expf(s2) : 0.f;
            float p3 = (j3i < nj) ? __expf(s3) : 0.f;
            uint4 w0 = *(const uint4*)(h2b + ((unsigned)(u0 << 6) + sub * 8));
            uint4 w1 = *(const uint4*)(h2b + ((unsigned)(u1 << 6) + sub * 8));
            uint4 w2 = *(const uint4*)(h2b + ((unsigned)(u2 << 6) + sub * 8));
            uint4 w3 = *(const uint4*)(h2b + ((unsigned)(u3 << 6) + sub * 8));
            sp += p0 + p1 + p2 + p3;
#define ACC8(P, W) \
            a[0] = fmaf(P, bflo(W.x), a[0]); a[1] = fmaf(P, bfhi(W.x), a[1]); \
            a[2] = fmaf(P, bflo(W.y), a[2]); a[3] = fmaf(P, bfhi(W.y), a[3]); \
            a[4] = fmaf(P, bflo(W.z), a[4]); a[5] = fmaf(P, bfhi(W.z), a[5]); \
            a[6] = fmaf(P, bflo(W.w), a[6]); a[7] = fmaf(P, bfhi(W.w), a[7]);
            ACC8(p0, w0) ACC8(p1, w1) ACC8(p2, w2) ACC8(p3, w3)
#undef ACC8
        }
    }
#pragma unroll
    for (int d = 8; d <= 32; d <<= 1) {
#pragma unroll
        for (int i = 0; i < 8; ++i) a[i] += __shfl_xor(a[i], d, 64);
        sp += __shfl_xor(sp, d, 64);
    }
    if (g == 0) {
        float inv = sp > 0.f ? 1.0f / sp : 0.f;
        float4 b0 = *(const float4*)(b2 + sub * 8);
        float4 b1v = *(const float4*)(b2 + sub * 8 + 4);
        float4 o0, o1;
        o0.x = a[0] * inv + b0.x; o0.y = a[1] * inv + b0.y;
        o0.z = a[2] * inv + b0.z; o0.w = a[3] * inv + b0.w;
        o1.x = a[4] * inv + b1v.x; o1.y = a[5] * inv + b1v.y;
        o1.z = a[6] * inv + b1v.z; o1.w = a[7] * inv + b1v.w;
        *(float4*)(out + (size_t)v * NCLS + sub * 8) = o0;
        *(float4*)(out + (size_t)v * NCLS + sub * 8 + 4) = o1;
    }
}

extern "C" void kernel_launch(void* const* d_in, const int* in_sizes, int n_in,
                              void* d_out, int out_size, void* d_ws, size_t ws_size,
                              hipStream_t stream) {
    const float* x   = (const float*)d_in[0];
    const int*   src = (const int*)d_in[1];
    const int*   dst = (const int*)d_in[2];
    const float* W1  = (const float*)d_in[3];
    const float* al1 = (const float*)d_in[4];
    const float* ar1 = (const float*)d_in[5];
    const float* b1  = (const float*)d_in[6];
    const float* W2  = (const float*)d_in[7];
    const float* al2 = (const float*)d_in[8];
    const float* ar2 = (const float*)d_in[9];
    const float* b2  = (const float*)d_in[10];
    float* out = (float*)d_out;

    // workspace layout (~90 MB)
    float* el1 = (float*)d_ws;                                 // N*HEADS f32
    float* er1 = el1 + (size_t)NNODES * HEADS;
    float* el2 = er1 + (size_t)NNODES * HEADS;                 // N
    float* er2 = el2 + NNODES;
    unsigned short* h1b = (unsigned short*)(er2 + NNODES);     // N*HID bf16
    unsigned short* hfb = h1b + (size_t)NNODES * HID;          // N*HID bf16
    unsigned short* h2b = hfb + (size_t)NNODES * HID;          // N*NCLS bf16
    int* row_off    = (int*)(h2b + (size_t)NNODES * NCLS);     // N (+pad)
    int* row_cnt    = row_off + NNODES + 4;                    // N
    int* sorted_src = row_cnt + NNODES;                        // NBUCK*BCAP (gapped)
    short* W1T      = (short*)(sorted_src + NBUCK * BCAP);     // HID*IN_DIM bf16
    short* W2T      = W1T + (size_t)HID * IN_DIM;              // NCLS*HID bf16
    int* gcur       = (int*)(W2T + (size_t)NCLS * HID);        // NBUCK
    unsigned* pairs = (unsigned*)(gcur + NBUCK + 1);           // NBUCK*BCAP packed u32

    // ---- bucketized CSR build (fixed-capacity, no hist/scan) ----
    init_gcur_kernel<<<(NBUCK + 255) / 256, 256, 0, stream>>>(gcur);
    bucket_scatter_kernel<<<NBBLK, 256, 0, stream>>>(src, dst, gcur, pairs);
    bucket_csr_kernel<<<NBUCK, 256, 0, stream>>>(pairs, gcur, row_off, row_cnt, sorted_src);

    // ---- layer 1 ----
    prep_w1t_kernel<<<(IN_DIM * HID + 255) / 256, 256, 0, stream>>>(W1, W1T);
    prep_w2t_kernel<<<(HID * NCLS + 255) / 256, 256, 0, stream>>>(W2, W2T);
    gemm1_kernel<<<(NNODES + 127) / 128, 256, 0, stream>>>(x, W1T, h1b);
    attn_scores_kernel<<<(NNODES * HEADS + 255) / 256, 256, 0, stream>>>(h1b, al1, ar1, el1, er1);
    aggregate1_kernel<<<2048, 256, 0, stream>>>(h1b, el1, er1, row_off, row_cnt, sorted_src,
                                                b1, hfb);

    // ---- layer 2 ----
    gemm2_kernel<<<(NNODES + 127) / 128, 256, 0, stream>>>(hfb, W2T, al2, ar2, h2b, el2, er2);
    aggregate2_kernel<<<(NNODES + 3) / 4, 256, 0, stream>>>(h2b, el2, er2, row_off, row_cnt,
                                                            sorted_src, b2, out);
}

// Round 14
// 244.231 us; speedup vs baseline: 1.2851x; 1.0686x over previous
//
#include <hip/hip_runtime.h>
#include <hip/hip_bf16.h>
#include <cstdint>
#include <cstddef>

#define NNODES 100000
#define NEDGES 1600000
#define IN_DIM 256
#define HID 128
#define HEADS 8
#define DH 16
#define NCLS 64
#define SLOPE 0.2f

#define NBUCK 391              // (NNODES+255)>>8, 256 nodes per bucket
#define BCAP 5120              // fixed bucket capacity (Poisson mean 4092, +16 sigma)
#define EPB 4000               // edges per scatter block (400*4000 = E)
#define NBBLK 400
#define G1BLK 782              // (NNODES+127)/128
#define ATTNBLK 3125           // NNODES*HEADS/256

typedef __attribute__((ext_vector_type(8))) short bf16x8;
typedef __attribute__((ext_vector_type(4))) float f32x4;

static __device__ __forceinline__ unsigned short f2bf(float f) {
    __hip_bfloat16 h = __float2bfloat16(f);
    unsigned short r;
    __builtin_memcpy(&r, &h, sizeof(r));
    return r;
}
static __device__ __forceinline__ float bflo(unsigned int w) {
    union { uint32_t u; float f; } c; c.u = w << 16; return c.f;
}
static __device__ __forceinline__ float bfhi(unsigned int w) {
    union { uint32_t u; float f; } c; c.u = w & 0xFFFF0000u; return c.f;
}

// ---------------- stage 0: W1T + W2T bf16 transposes + gcur init (one launch) ----------------
__global__ __launch_bounds__(256) void stage0_prep_kernel(const float* __restrict__ W1,
                                                          const float* __restrict__ W2,
                                                          short* __restrict__ W1T,
                                                          short* __restrict__ W2T,
                                                          int* __restrict__ gcur) {
    int idx = blockIdx.x * 256 + threadIdx.x;
    if (idx < IN_DIM * HID) {
        int k = idx >> 7, n = idx & 127;
        W1T[n * IN_DIM + k] = (short)f2bf(W1[idx]);
    } else if (idx < IN_DIM * HID + HID * NCLS) {
        int j = idx - IN_DIM * HID;
        int k = j >> 6, n = j & 63;
        W2T[n * HID + k] = (short)f2bf(W2[j]);
    } else {
        int b = idx - IN_DIM * HID - HID * NCLS;
        if (b < NBUCK) gcur[b] = b * BCAP;
    }
}

// ---------------- stage 1 (fused): bucket_scatter [0,400) || gemm1 [400,1182) ----------------
__global__ __launch_bounds__(256) void stage1_kernel(const int* __restrict__ src,
                                                     const int* __restrict__ dst,
                                                     int* __restrict__ gcur,
                                                     unsigned* __restrict__ pairs,
                                                     const float* __restrict__ x,
                                                     const short* __restrict__ W1T,
                                                     unsigned short* __restrict__ h1b) {
    __shared__ __align__(16) char smem[128 * 40 * 2];   // 10240 B (gemm) >= 3128 B (scatter)
    const int tid = threadIdx.x;

    if (blockIdx.x < NBBLK) {
        // ----- bucketed scatter of (dst-local, src) packed pairs -----
        int* cnt  = (int*)smem;          // NBUCK
        int* base = cnt + NBUCK;         // NBUCK
        for (int i = tid; i < NBUCK; i += 256) cnt[i] = 0;
        __syncthreads();
        const int eb = blockIdx.x * EPB;
        for (int i = tid; i < EPB; i += 256) atomicAdd(&cnt[dst[eb + i] >> 8], 1);
        __syncthreads();
        for (int b = tid; b < NBUCK; b += 256) {
            int c = cnt[b];
            base[b] = c ? atomicAdd(&gcur[b], c) : 0;
            cnt[b] = 0;   // becomes cursor
        }
        __syncthreads();
        for (int i = tid; i < EPB; i += 256) {
            int d = dst[eb + i], s = src[eb + i];
            int b = d >> 8;
            int p = base[b] + atomicAdd(&cnt[b], 1);
            pairs[p] = ((unsigned)(d & 255) << 24) | (unsigned)s;   // src < 2^24
        }
        return;
    }

    // ----- bf16 MFMA GEMM1: h1b = x @ W1 -----
    short* Asl = (short*)smem;   // [128*40]
    const int brow = (blockIdx.x - NBBLK) * 128;
    const int wid = tid >> 6, lane = tid & 63;
    const int wm = (wid >> 1) * 64, wn = (wid & 1) * 64;
    const int mr = lane & 15;
    const int ks = lane >> 4;
    const int sr = tid >> 1;
    const int sch = tid & 1;
    const int grow = brow + sr;
    const bool rowok = grow < NNODES;
    const float* xrow = x + (size_t)grow * IN_DIM + sch * 16;

    f32x4 acc[4][4];
#pragma unroll
    for (int i = 0; i < 4; ++i)
#pragma unroll
        for (int j = 0; j < 4; ++j) acc[i][j] = (f32x4){0.f, 0.f, 0.f, 0.f};

    float4 v0 = {0,0,0,0}, v1 = {0,0,0,0}, v2 = {0,0,0,0}, v3 = {0,0,0,0};
    if (rowok) {
        v0 = *(const float4*)(xrow + 0);
        v1 = *(const float4*)(xrow + 4);
        v2 = *(const float4*)(xrow + 8);
        v3 = *(const float4*)(xrow + 12);
    }

    for (int k0 = 0; k0 < IN_DIM; k0 += 32) {
        bf16x8 p0, p1;
        p0[0] = (short)f2bf(v0.x); p0[1] = (short)f2bf(v0.y);
        p0[2] = (short)f2bf(v0.z); p0[3] = (short)f2bf(v0.w);
        p0[4] = (short)f2bf(v1.x); p0[5] = (short)f2bf(v1.y);
        p0[6] = (short)f2bf(v1.z); p0[7] = (short)f2bf(v1.w);
        p1[0] = (short)f2bf(v2.x); p1[1] = (short)f2bf(v2.y);
        p1[2] = (short)f2bf(v2.z); p1[3] = (short)f2bf(v2.w);
        p1[4] = (short)f2bf(v3.x); p1[5] = (short)f2bf(v3.y);
        p1[6] = (short)f2bf(v3.z); p1[7] = (short)f2bf(v3.w);
        if (k0 + 32 < IN_DIM && rowok) {
            v0 = *(const float4*)(xrow + k0 + 32 + 0);
            v1 = *(const float4*)(xrow + k0 + 32 + 4);
            v2 = *(const float4*)(xrow + k0 + 32 + 8);
            v3 = *(const float4*)(xrow + k0 + 32 + 12);
        }
        __syncthreads();
        *(bf16x8*)(Asl + sr * 40 + sch * 16 + 0) = p0;
        *(bf16x8*)(Asl + sr * 40 + sch * 16 + 8) = p1;
        __syncthreads();

        bf16x8 af[4], bfr[4];
#pragma unroll
        for (int i = 0; i < 4; ++i)
            af[i] = *(const bf16x8*)(Asl + (wm + i * 16 + mr) * 40 + ks * 8);
#pragma unroll
        for (int j = 0; j < 4; ++j)
            bfr[j] = *(const bf16x8*)(W1T + (size_t)(wn + j * 16 + mr) * IN_DIM + k0 + ks * 8);
#pragma unroll
        for (int i = 0; i < 4; ++i)
#pragma unroll
            for (int j = 0; j < 4; ++j)
                acc[i][j] = __builtin_amdgcn_mfma_f32_16x16x32_bf16(af[i], bfr[j], acc[i][j], 0, 0, 0);
    }

#pragma unroll
    for (int i = 0; i < 4; ++i) {
#pragma unroll
        for (int j = 0; j < 4; ++j) {
            int col = wn + j * 16 + mr;
#pragma unroll
            for (int r = 0; r < 4; ++r) {
                int row = brow + wm + i * 16 + ks * 4 + r;
                if (row < NNODES) h1b[(size_t)row * HID + col] = f2bf(acc[i][j][r]);
            }
        }
    }
}

// ---------------- stage 2 (fused): bucket_csr [0,391) || attn_scores [391,3516) ----------------
__global__ __launch_bounds__(256) void stage2_kernel(const unsigned* __restrict__ pairs,
                                                     const int* __restrict__ gcur,
                                                     int* __restrict__ row_off,
                                                     int* __restrict__ row_cnt,
                                                     int* __restrict__ sorted_src,
                                                     const unsigned short* __restrict__ h1b,
                                                     const float* __restrict__ al,
                                                     const float* __restrict__ ar,
                                                     float* __restrict__ el,
                                                     float* __restrict__ er) {
    __shared__ int ncnt[256];
    __shared__ int nbase[256];
    __shared__ int ws[4];
    const int tid = threadIdx.x;

    if (blockIdx.x < NBUCK) {
        // ----- per-bucket local CSR -----
        const int lane = tid & 63, wid = tid >> 6;
        const int b = blockIdx.x;
        const int nbeg = b << 8;
        const int ebeg = b * BCAP;
        const int eend = gcur[b];

        ncnt[tid] = 0;
        __syncthreads();
        for (int pos = ebeg + tid; pos < eend; pos += 256)
            atomicAdd(&ncnt[pairs[pos] >> 24], 1);
        __syncthreads();
        int v = ncnt[tid];
        int x = v;
#pragma unroll
        for (int d = 1; d < 64; d <<= 1) {
            int y = __shfl_up(x, d, 64);
            if (lane >= d) x += y;
        }
        if (lane == 63) ws[wid] = x;
        __syncthreads();
        int woff = 0;
#pragma unroll
        for (int i = 0; i < 4; ++i) if (i < wid) woff += ws[i];
        int gb = ebeg + woff + (x - v);
        int node = nbeg + tid;
        if (node < NNODES) { row_off[node] = gb; row_cnt[node] = v; }
        nbase[tid] = gb;
        ncnt[tid] = 0;   // becomes cursor
        __syncthreads();
        for (int pos = ebeg + tid; pos < eend; pos += 256) {
            unsigned pr = pairs[pos];
            int l = pr >> 24;
            int p = nbase[l] + atomicAdd(&ncnt[l], 1);
            sorted_src[p] = (int)(pr & 0xFFFFFFu);
        }
        return;
    }

    // ----- layer-1 attention scores -----
    int idx = (blockIdx.x - NBUCK) * 256 + tid;
    if (idx >= NNODES * HEADS) return;
    int hd = idx & (HEADS - 1);
    const uint4* hp = (const uint4*)(h1b + (size_t)idx * DH);
    uint4 A = hp[0], B = hp[1];
    unsigned int w[8] = {A.x, A.y, A.z, A.w, B.x, B.y, B.z, B.w};
    float a = 0.f, c = 0.f;
#pragma unroll
    for (int i = 0; i < 8; ++i) {
        float lo = bflo(w[i]), hi = bfhi(w[i]);
        a = fmaf(lo, al[hd * DH + 2 * i], a);
        a = fmaf(hi, al[hd * DH + 2 * i + 1], a);
        c = fmaf(lo, ar[hd * DH + 2 * i], c);
        c = fmaf(hi, ar[hd * DH + 2 * i + 1], c);
    }
    el[idx] = a;
    er[idx] = c;
}

// ---------------- bf16 MFMA GEMM2: h2b = hf @ W2, fused el2/er2 ----------------
__global__ __launch_bounds__(256) void gemm2_kernel(const unsigned short* __restrict__ hfb,
                                                    const short* __restrict__ W2T,
                                                    const float* __restrict__ al2,
                                                    const float* __restrict__ ar2,
                                                    unsigned short* __restrict__ h2b,
                                                    float* __restrict__ el2,
                                                    float* __restrict__ er2) {
    __shared__ short A[128 * 136];
    const int tid = threadIdx.x;
    const int brow = blockIdx.x * 128;
    {
        int r = tid >> 1, half = tid & 1;
        int grow = brow + r;
        uint4* lp = (uint4*)(A + r * 136 + half * 64);
        if (grow < NNODES) {
            const uint4* gp = (const uint4*)(hfb + (size_t)grow * HID + half * 64);
#pragma unroll
            for (int i = 0; i < 8; ++i) lp[i] = gp[i];
        } else {
            uint4 z = {0, 0, 0, 0};
#pragma unroll
            for (int i = 0; i < 8; ++i) lp[i] = z;
        }
    }
    __syncthreads();

    const int wid = tid >> 6, lane = tid & 63;
    const int mr = lane & 15, ks = lane >> 4;
    const int wrow = wid * 32;

    f32x4 acc[2][4];
#pragma unroll
    for (int i = 0; i < 2; ++i)
#pragma unroll
        for (int j = 0; j < 4; ++j) acc[i][j] = (f32x4){0.f, 0.f, 0.f, 0.f};

#pragma unroll
    for (int kk = 0; kk < 4; ++kk) {
        const int k0 = kk * 32;
        bf16x8 af[2], bfr[4];
#pragma unroll
        for (int i = 0; i < 2; ++i)
            af[i] = *(const bf16x8*)(A + (wrow + i * 16 + mr) * 136 + k0 + ks * 8);
#pragma unroll
        for (int j = 0; j < 4; ++j)
            bfr[j] = *(const bf16x8*)(W2T + (size_t)(j * 16 + mr) * HID + k0 + ks * 8);
#pragma unroll
        for (int i = 0; i < 2; ++i)
#pragma unroll
            for (int j = 0; j < 4; ++j)
                acc[i][j] = __builtin_amdgcn_mfma_f32_16x16x32_bf16(af[i], bfr[j], acc[i][j], 0, 0, 0);
    }

    float al2v[4], ar2v[4];
#pragma unroll
    for (int j = 0; j < 4; ++j) { al2v[j] = al2[j * 16 + mr]; ar2v[j] = ar2[j * 16 + mr]; }

    float pl[2][4] = {}, pr[2][4] = {};
#pragma unroll
    for (int i = 0; i < 2; ++i) {
#pragma unroll
        for (int j = 0; j < 4; ++j) {
#pragma unroll
            for (int r = 0; r < 4; ++r) {
                float vvv = acc[i][j][r];
                pl[i][r] = fmaf(vvv, al2v[j], pl[i][r]);
                pr[i][r] = fmaf(vvv, ar2v[j], pr[i][r]);
                int row = brow + wrow + i * 16 + ks * 4 + r;
                if (row < NNODES) h2b[(size_t)row * NCLS + j * 16 + mr] = f2bf(vvv);
            }
        }
    }
#pragma unroll
    for (int d = 1; d <= 8; d <<= 1) {
#pragma unroll
        for (int i = 0; i < 2; ++i)
#pragma unroll
            for (int r = 0; r < 4; ++r) {
                pl[i][r] += __shfl_xor(pl[i][r], d, 64);
                pr[i][r] += __shfl_xor(pr[i][r], d, 64);
            }
    }
    if (mr == 0) {
#pragma unroll
        for (int i = 0; i < 2; ++i)
#pragma unroll
            for (int r = 0; r < 4; ++r) {
                int row = brow + wrow + i * 16 + ks * 4 + r;
                if (row < NNODES) { el2[row] = pl[i][r]; er2[row] = pr[i][r]; }
            }
    }
}

// ---------------- layer-1 aggregation: inline scores, 4 groups x 16 lanes ----------------
__global__ __launch_bounds__(256) void aggregate1_kernel(const unsigned short* __restrict__ h1b,
                                                         const float* __restrict__ el1,
                                                         const float* __restrict__ er1,
                                                         const int* __restrict__ row_off,
                                                         const int* __restrict__ row_cnt,
                                                         const int* __restrict__ sorted_src,
                                                         const float* __restrict__ b1,
                                                         unsigned short* __restrict__ hfb) {
    __shared__ float b1s[HID];
    const int tid = threadIdx.x;
    if (tid < HID) b1s[tid] = b1[tid];
    __syncthreads();

    const int wid = tid >> 6, lane = tid & 63;
    const int g = lane >> 4, sub = lane & 15, hd = sub >> 1;

    for (int v = blockIdx.x * 4 + wid; v < NNODES; v += gridDim.x * 4) {
        const int beg = row_off[v];
        const int end = beg + row_cnt[v];
        const float er_v = er1[v * HEADS + hd];
        float a[8] = {0.f, 0.f, 0.f, 0.f, 0.f, 0.f, 0.f, 0.f};
        float sp = 0.f;
        for (int j0 = beg; j0 < end; j0 += 64) {
            const int nj = min(64, end - j0);
            const int nit = (nj + 3) >> 2;
            int us = (j0 + lane < end) ? sorted_src[j0 + lane] : 0;
            for (int ib = 0; ib < nit; ib += 4) {
                int j0i = g + 4 * (ib + 0), j1i = g + 4 * (ib + 1);
                int j2i = g + 4 * (ib + 2), j3i = g + 4 * (ib + 3);
                int u0 = __shfl(us, j0i, 64);
                int u1 = __shfl(us, j1i, 64);
                int u2 = __shfl(us, j2i, 64);
                int u3 = __shfl(us, j3i, 64);
                uint4 w0 = *(const uint4*)(h1b + ((unsigned)(u0 << 7) + sub * 8));
                uint4 w1 = *(const uint4*)(h1b + ((unsigned)(u1 << 7) + sub * 8));
                uint4 w2 = *(const uint4*)(h1b + ((unsigned)(u2 << 7) + sub * 8));
                uint4 w3 = *(const uint4*)(h1b + ((unsigned)(u3 << 7) + sub * 8));
                float e0 = el1[(unsigned)(u0 << 3) + hd];
                float e1 = el1[(unsigned)(u1 << 3) + hd];
                float e2 = el1[(unsigned)(u2 << 3) + hd];
                float e3 = el1[(unsigned)(u3 << 3) + hd];
                float s0 = e0 + er_v; s0 = s0 > 0.f ? s0 : SLOPE * s0;
                float s1 = e1 + er_v; s1 = s1 > 0.f ? s1 : SLOPE * s1;
                float s2 = e2 + er_v; s2 = s2 > 0.f ? s2 : SLOPE * s2;
                float s3 = e3 + er_v; s3 = s3 > 0.f ? s3 : SLOPE * s3;
                float p0 = (j0i < nj) ? __expf(s0) : 0.f;
                float p1 = (j1i < nj) ? __expf(s1) : 0.f;
                float p2 = (j2i < nj) ? __expf(s2) : 0.f;
                float p3 = (j3i < nj) ? __expf(s3) : 0.f;
                sp += p0 + p1 + p2 + p3;
#define ACC8(P, W) \
                a[0] = fmaf(P, bflo(W.x), a[0]); a[1] = fmaf(P, bfhi(W.x), a[1]); \
                a[2] = fmaf(P, bflo(W.y), a[2]); a[3] = fmaf(P, bfhi(W.y), a[3]); \
                a[4] = fmaf(P, bflo(W.z), a[4]); a[5] = fmaf(P, bfhi(W.z), a[5]); \
                a[6] = fmaf(P, bflo(W.w), a[6]); a[7] = fmaf(P, bfhi(W.w), a[7]);
                ACC8(p0, w0) ACC8(p1, w1) ACC8(p2, w2) ACC8(p3, w3)
#undef ACC8
            }
        }
#pragma unroll
        for (int d = 16; d <= 32; d <<= 1) {
#pragma unroll
            for (int i = 0; i < 8; ++i) a[i] += __shfl_xor(a[i], d, 64);
            sp += __shfl_xor(sp, d, 64);
        }
        float inv = sp > 0.f ? 1.0f / sp : 0.f;
        float f[8];
#pragma unroll
        for (int i = 0; i < 8; ++i) {
            float t = a[i] * inv + b1s[sub * 8 + i];
            t = t > 0.f ? t : __expf(t) - 1.f;   // ELU via hw exp
            t = t > 0.f ? t : __expf(t) - 1.f;
            f[i] = t;
        }
        if (g == 0) {
            uint4 w;
            w.x = (unsigned)f2bf(f[0]) | ((unsigned)f2bf(f[1]) << 16);
            w.y = (unsigned)f2bf(f[2]) | ((unsigned)f2bf(f[3]) << 16);
            w.z = (unsigned)f2bf(f[4]) | ((unsigned)f2bf(f[5]) << 16);
            w.w = (unsigned)f2bf(f[6]) | ((unsigned)f2bf(f[7]) << 16);
            *(uint4*)(hfb + (size_t)v * HID + sub * 8) = w;
        }
    }
}

// ---------------- layer-2 aggregation: inline scores, 8 groups x 8 lanes ----------------
__global__ __launch_bounds__(256) void aggregate2_kernel(const unsigned short* __restrict__ h2b,
                                                         const float* __restrict__ el2,
                                                         const float* __restrict__ er2,
                                                         const int* __restrict__ row_off,
                                                         const int* __restrict__ row_cnt,
                                                         const int* __restrict__ sorted_src,
                                                         const float* __restrict__ b2,
                                                         float* __restrict__ out) {
    const int tid = threadIdx.x;
    const int v = blockIdx.x * 4 + (tid >> 6);
    if (v >= NNODES) return;
    const int lane = tid & 63, g = lane >> 3, sub = lane & 7;
    const int beg = row_off[v];
    const int end = beg + row_cnt[v];
    const float er_v = er2[v];
    float a[8] = {0.f, 0.f, 0.f, 0.f, 0.f, 0.f, 0.f, 0.f};
    float sp = 0.f;
    for (int j0 = beg; j0 < end; j0 += 64) {
        const int nj = min(64, end - j0);
        const int nit = (nj + 7) >> 3;
        bool valid = j0 + lane < end;
        int us = valid ? sorted_src[j0 + lane] : 0;
        float ev = valid ? el2[us] : 0.f;
        for (int ib = 0; ib < nit; ib += 4) {
            int j0i = g + 8 * (ib + 0), j1i = g + 8 * (ib + 1);
            int j2i = g + 8 * (ib + 2), j3i = g + 8 * (ib + 3);
            int u0 = __shfl(us, j0i, 64);
            int u1 = __shfl(us, j1i, 64);
            int u2 = __shfl(us, j2i, 64);
            int u3 = __shfl(us, j3i, 64);
            float s0 = __shfl(ev, j0i, 64) + er_v; s0 = s0 > 0.f ? s0 : SLOPE * s0;
            float s1 = __shfl(ev, j1i, 64) + er_v; s1 = s1 > 0.f ? s1 : SLOPE * s1;
            float s2 = __shfl(ev, j2i, 64) + er_v; s2 = s2 > 0.f ? s2 : SLOPE * s2;
            float s3 = __shfl(ev, j3i, 64) + er_v; s3 = s3 > 0.f ? s3 : SLOPE * s3;
            float p0 = (j0i < nj) ? __expf(s0) : 0.f;
            float p1 = (j1i < nj) ? __expf(s1) : 0.f;
            float p2 = (j2i < nj) ? __expf(s2) : 0.f;
            float p3 = (j3i < nj) ? __expf(s3) : 0.f;
            uint4 w0 = *(const uint4*)(h2b + ((unsigned)(u0 << 6) + sub * 8));
            uint4 w1 = *(const uint4*)(h2b + ((unsigned)(u1 << 6) + sub * 8));
            uint4 w2 = *(const uint4*)(h2b + ((unsigned)(u2 << 6) + sub * 8));
            uint4 w3 = *(const uint4*)(h2b + ((unsigned)(u3 << 6) + sub * 8));
            sp += p0 + p1 + p2 + p3;
#define ACC8(P, W) \
            a[0] = fmaf(P, bflo(W.x), a[0]); a[1] = fmaf(P, bfhi(W.x), a[1]); \
            a[2] = fmaf(P, bflo(W.y), a[2]); a[3] = fmaf(P, bfhi(W.y), a[3]); \
            a[4] = fmaf(P, bflo(W.z), a[4]); a[5] = fmaf(P, bfhi(W.z), a[5]); \
            a[6] = fmaf(P, bflo(W.w), a[6]); a[7] = fmaf(P, bfhi(W.w), a[7]);
            ACC8(p0, w0) ACC8(p1, w1) ACC8(p2, w2) ACC8(p3, w3)
#undef ACC8
        }
    }
#pragma unroll
    for (int d = 8; d <= 32; d <<= 1) {
#pragma unroll
        for (int i = 0; i < 8; ++i) a[i] += __shfl_xor(a[i], d, 64);
        sp += __shfl_xor(sp, d, 64);
    }
    if (g == 0) {
        float inv = sp > 0.f ? 1.0f / sp : 0.f;
        float4 b0 = *(const float4*)(b2 + sub * 8);
        float4 b1v = *(const float4*)(b2 + sub * 8 + 4);
        float4 o0, o1;
        o0.x = a[0] * inv + b0.x; o0.y = a[1] * inv + b0.y;
        o0.z = a[2] * inv + b0.z; o0.w = a[3] * inv + b0.w;
        o1.x = a[4] * inv + b1v.x; o1.y = a[5] * inv + b1v.y;
        o1.z = a[6] * inv + b1v.z; o1.w = a[7] * inv + b1v.w;
        *(float4*)(out + (size_t)v * NCLS + sub * 8) = o0;
        *(float4*)(out + (size_t)v * NCLS + sub * 8 + 4) = o1;
    }
}

extern "C" void kernel_launch(void* const* d_in, const int* in_sizes, int n_in,
                              void* d_out, int out_size, void* d_ws, size_t ws_size,
                              hipStream_t stream) {
    const float* x   = (const float*)d_in[0];
    const int*   src = (const int*)d_in[1];
    const int*   dst = (const int*)d_in[2];
    const float* W1  = (const float*)d_in[3];
    const float* al1 = (const float*)d_in[4];
    const float* ar1 = (const float*)d_in[5];
    const float* b1  = (const float*)d_in[6];
    const float* W2  = (const float*)d_in[7];
    const float* al2 = (const float*)d_in[8];
    const float* ar2 = (const float*)d_in[9];
    const float* b2  = (const float*)d_in[10];
    float* out = (float*)d_out;

    // workspace layout (~90 MB)
    float* el1 = (float*)d_ws;                                 // N*HEADS f32
    float* er1 = el1 + (size_t)NNODES * HEADS;
    float* el2 = er1 + (size_t)NNODES * HEADS;                 // N
    float* er2 = el2 + NNODES;
    unsigned short* h1b = (unsigned short*)(er2 + NNODES);     // N*HID bf16
    unsigned short* hfb = h1b + (size_t)NNODES * HID;          // N*HID bf16
    unsigned short* h2b = hfb + (size_t)NNODES * HID;          // N*NCLS bf16
    int* row_off    = (int*)(h2b + (size_t)NNODES * NCLS);     // N (+pad)
    int* row_cnt    = row_off + NNODES + 4;                    // N
    int* sorted_src = row_cnt + NNODES;                        // NBUCK*BCAP (gapped)
    short* W1T      = (short*)(sorted_src + NBUCK * BCAP);     // HID*IN_DIM bf16
    short* W2T      = W1T + (size_t)HID * IN_DIM;              // NCLS*HID bf16
    int* gcur       = (int*)(W2T + (size_t)NCLS * HID);        // NBUCK
    unsigned* pairs = (unsigned*)(gcur + NBUCK + 1);           // NBUCK*BCAP packed u32

    // stage 0: weight transposes + gcur init (one launch)
    const int prep_total = IN_DIM * HID + HID * NCLS + NBUCK;
    stage0_prep_kernel<<<(prep_total + 255) / 256, 256, 0, stream>>>(W1, W2, W1T, W2T, gcur);

    // stage 1: bucket scatter || gemm1
    stage1_kernel<<<NBBLK + G1BLK, 256, 0, stream>>>(src, dst, gcur, pairs, x, W1T, h1b);

    // stage 2: bucket CSR || attn scores
    stage2_kernel<<<NBUCK + ATTNBLK, 256, 0, stream>>>(pairs, gcur, row_off, row_cnt, sorted_src,
                                                       h1b, al1, ar1, el1, er1);

    // layer-1 aggregation
    aggregate1_kernel<<<2048, 256, 0, stream>>>(h1b, el1, er1, row_off, row_cnt, sorted_src,
                                                b1, hfb);

    // layer 2
    gemm2_kernel<<<(NNODES + 127) / 128, 256, 0, stream>>>(hfb, W2T, al2, ar2, h2b, el2, er2);
    aggregate2_kernel<<<(NNODES + 3) / 4, 256, 0, stream>>>(h2b, el2, er2, row_off, row_cnt,
                                                            sorted_src, b2, out);
}